// Round 16
// baseline (227.026 us; speedup 1.0000x reference)
//
#include <hip/hip_runtime.h>
#include <hip/hip_fp16.h>

typedef unsigned short u16;
using f32x4 = __attribute__((ext_vector_type(4))) float;
using half8 = __attribute__((ext_vector_type(8))) _Float16;
using us4   = __attribute__((ext_vector_type(4))) unsigned short;

#define N_PTS 8192
#define D_DIM 768
#define TOPK  21
#define KSTEPS 12
#define CAPL  5          // lambda/tile-side ~0.94 -> P(>5) ~3e-4, ~200 spills total
#define CAPG  192        // E[cand/row]=60, +17 sigma
#define ZTAU  2.44f      // tau_i = n_i + 768 - ZTAU*sqrt(1536+4 n_i) -> E=60/row

// ---------------- async global->LDS (16B per lane) ----------------
__device__ __forceinline__ void gload16(const void* g, void* l) {
    __builtin_amdgcn_global_load_lds(
        (const __attribute__((address_space(1))) void*)g,
        (__attribute__((address_space(3))) void*)l,
        16, 0, 0);
}

// ---------------- wave (64-lane) reductions ----------------
__device__ __forceinline__ int wred_sum_i(int c) {
#pragma unroll
    for (int o = 32; o >= 1; o >>= 1) c += __shfl_xor(c, o, 64);
    return c;
}
__device__ __forceinline__ float wred_sum_f(float c) {
#pragma unroll
    for (int o = 32; o >= 1; o >>= 1) c += __shfl_xor(c, o, 64);
    return c;
}
__device__ __forceinline__ float wred_min_f(float c) {
#pragma unroll
    for (int o = 32; o >= 1; o >>= 1) c = fminf(c, __shfl_xor(c, o, 64));
    return c;
}

// branch-free sorted top-k insert (ascending), rescue path only
__device__ __forceinline__ void topk_insert(float (&t)[TOPK], float x) {
    if (x >= t[TOPK - 1]) return;
#pragma unroll
    for (int i = TOPK - 1; i >= 1; --i) {
        float tp = t[i - 1];
        t[i] = (x < tp) ? tp : fminf(x, t[i]);
    }
    t[0] = fminf(t[0], x);
}

// ---------------- kernel 1: fp32 -> fp16 + row norms (vectorized) ----
__global__ __launch_bounds__(256) void prep_kernel(const float* __restrict__ X,
                                                   u16* __restrict__ Xh,
                                                   float* __restrict__ norms,
                                                   int* __restrict__ cnt_g) {
    const int tid  = threadIdx.x;
    const int lane = tid & 63;
    const int row  = blockIdx.x * 4 + (tid >> 6);
    const float4* xr = (const float4*)(X + (size_t)row * D_DIM);
    us4* hr = (us4*)(Xh + (size_t)row * D_DIM);
    float s = 0.f;
#pragma unroll
    for (int j = 0; j < 3; ++j) {
        const float4 v = xr[lane + j * 64];
        _Float16 h0 = (_Float16)v.x, h1 = (_Float16)v.y,
                 h2 = (_Float16)v.z, h3 = (_Float16)v.w;
        us4 u;
        u[0] = __builtin_bit_cast(u16, h0);
        u[1] = __builtin_bit_cast(u16, h1);
        u[2] = __builtin_bit_cast(u16, h2);
        u[3] = __builtin_bit_cast(u16, h3);
        hr[lane + j * 64] = u;
        const float f0 = (float)h0, f1 = (float)h1, f2 = (float)h2, f3 = (float)h3;
        s += f0 * f0 + f1 * f1 + f2 * f2 + f3 * f3;
    }
#pragma unroll
    for (int o = 32; o >= 1; o >>= 1) s += __shfl_down(s, o, 64);
    if (lane == 0) {
        norms[row] = s;
        cnt_g[row] = 0;
    }
}

// ---------------- kernel 2: SYMMETRIC upper-triangle GEMM + two-sided filter ----
// 2080 = 64*65/2 tiles (i<=j). LDS exactly 40960 B -> 4 blocks/CU.
// K-loop restructured: frag-preload to regs + lgkmcnt(0) + barrier, THEN issue
// next tile's stage under the 32-MFMA cover -> next vmcnt(0) is ~free.
__global__ __launch_bounds__(256, 4) void gemm_filter_sym(const u16* __restrict__ Xh,
                                                          const float* __restrict__ norms,
                                                          float* __restrict__ cand_g,
                                                          int* __restrict__ cnt_g) {
    __shared__ __align__(16) u16 As[128 * 64];       // 16384 B
    __shared__ __align__(16) u16 Bs[128 * 64];       // 16384 B
    __shared__ float candR[128 * CAPL];              //  2560 B
    __shared__ float candC[128 * CAPL];              //  2560 B
    __shared__ int   cntR[128];                      //   512 B
    __shared__ int   cntC[128];                      //   512 B
    __shared__ float hNa[128], hNb[128], hCr[128], hCc[128];  // 2048 B => 40960

    const int tid  = threadIdx.x;
    const int lane = tid & 63;
    const int wid  = tid >> 6;
    const int wr   = wid >> 1;
    const int wc   = wid & 1;
    const int l16  = lane >> 4;
    const int l15  = lane & 15;

    // XCD swizzle (2080 = 8 * 260) then triangular decode: b = j*(j+1)/2 + i, i<=j
    const int b = (blockIdx.x & 7) * 260 + (blockIdx.x >> 3);
    int j = (int)((sqrtf(8.0f * (float)b + 1.0f) - 1.0f) * 0.5f);
    while ((j + 1) * (j + 2) / 2 <= b) ++j;
    while (j * (j + 1) / 2 > b) --j;
    const int i = b - j * (j + 1) / 2;
    const int r0 = i * 128;
    const int c0 = j * 128;
    const bool diag = (i == j);

    if (tid < 128) {
        const float na = norms[r0 + tid];
        const float nb = norms[c0 + tid];
        hNa[tid] = 0.5f * na;
        hNb[tid] = 0.5f * nb;
        hCr[tid] = 0.5f * (768.0f - ZTAU * sqrtf(1536.0f + 4.0f * na));
        hCc[tid] = 0.5f * (768.0f - ZTAU * sqrtf(1536.0f + 4.0f * nb));
        cntR[tid] = 0;
        cntC[tid] = 0;
    }

    // staging geometry: 8 lanes per 128B row; T2 source-side XOR swizzle
    const int rb  = tid >> 3;
    const int chS = (tid & 7) ^ ((tid >> 3) & 7);
    const int lofs = tid * 8;

    f32x4 acc[4][4];
#pragma unroll
    for (int m = 0; m < 4; ++m)
#pragma unroll
        for (int n = 0; n < 4; ++n) {
            f32x4 z = {0.f, 0.f, 0.f, 0.f};
            acc[m][n] = z;
        }

    // stage K-tile ks (8 gload16/thread)
    auto STAGE = [&](int ks) {
        const int kofs = ks * 64 + chS * 8;
#pragma unroll
        for (int it = 0; it < 4; ++it) {
            const int r = it * 32 + rb;
            gload16(Xh + (size_t)(r0 + r) * D_DIM + kofs, &As[it * 2048 + lofs]);
            gload16(Xh + (size_t)(c0 + r) * D_DIM + kofs, &Bs[it * 2048 + lofs]);
        }
    };

    STAGE(0);                            // prologue: one exposed drain only

    for (int ks = 0; ks < KSTEPS; ++ks) {
        // tile-ks loads were issued under previous iteration's MFMA cover
        asm volatile("s_waitcnt vmcnt(0)" ::: "memory");
        __builtin_amdgcn_sched_barrier(0);
        __builtin_amdgcn_s_barrier();    // barrier 1: tile ks visible to all
        __builtin_amdgcn_sched_barrier(0);

        // preload ALL fragments of this tile into registers
        half8 af[2][4], bf[2][4];
#pragma unroll
        for (int kk = 0; kk < 2; ++kk) {
#pragma unroll
            for (int m = 0; m < 4; ++m) {
                const int ra = wr * 64 + m * 16 + l15;
                const int ch = (kk * 4 + l16) ^ (ra & 7);
                af[kk][m] = *reinterpret_cast<const half8*>(&As[ra * 64 + ch * 8]);
            }
#pragma unroll
            for (int n = 0; n < 4; ++n) {
                const int rc = wc * 64 + n * 16 + l15;
                const int ch = (kk * 4 + l16) ^ (rc & 7);
                bf[kk][n] = *reinterpret_cast<const half8*>(&Bs[rc * 64 + ch * 8]);
            }
        }
        asm volatile("s_waitcnt lgkmcnt(0)" ::: "memory");  // frags landed in regs
        __builtin_amdgcn_sched_barrier(0);                  // rule #18 fence
        __builtin_amdgcn_s_barrier();    // barrier 2: ALL waves done reading LDS
        __builtin_amdgcn_sched_barrier(0);

        if (ks + 1 < KSTEPS) STAGE(ks + 1);   // overwrite-safe; flies under MFMA
        __builtin_amdgcn_sched_barrier(0);    // pin stage issue before MFMA block

        __builtin_amdgcn_s_setprio(1);
#pragma unroll
        for (int kk = 0; kk < 2; ++kk)
#pragma unroll
            for (int m = 0; m < 4; ++m)
#pragma unroll
                for (int n = 0; n < 4; ++n)
                    acc[m][n] = __builtin_amdgcn_mfma_f32_16x16x32_f16(
                        af[kk][m], bf[kk][n], acc[m][n], 0, 0, 0);
        __builtin_amdgcn_s_setprio(0);
    }

    // ---- two-sided filter epilogue, acc-domain compares ----
    __syncthreads();                     // hNa/cnt arrays ready for epilogue
    float hNb_n[4], hCc_n[4];
#pragma unroll
    for (int n = 0; n < 4; ++n) {
        const int ci = wc * 64 + n * 16 + l15;
        hNb_n[n] = hNb[ci];
        hCc_n[n] = hCc[ci];
    }

#pragma unroll
    for (int m = 0; m < 4; ++m)
#pragma unroll
        for (int r = 0; r < 4; ++r) {
            const int ri = wr * 64 + m * 16 + l16 * 4 + r;
            const float hna = hNa[ri];
            const float hcr = hCr[ri];
#pragma unroll
            for (int n = 0; n < 4; ++n) {
                const float d = acc[m][n][r];
                // rowHit: d2 < tau_row  <=>  acc > 0.5*nB - 0.5*C_row
                if (d > hNb_n[n] - hcr) {
                    const float val = 2.0f * (hna + hNb_n[n] - d);
                    const int idx2 = atomicAdd(&cntR[ri], 1);
                    if (idx2 < CAPL) candR[ri * CAPL + idx2] = val;
                    else {
                        const int g = atomicAdd(&cnt_g[r0 + ri], 1);
                        if (g < CAPG) cand_g[(size_t)(r0 + ri) * CAPG + g] = val;
                    }
                }
                // colHit: d2 < tau_col  <=>  acc > 0.5*nA - 0.5*C_col
                if (!diag && d > hna - hCc_n[n]) {
                    const int ci = wc * 64 + n * 16 + l15;
                    const float val = 2.0f * (hna + hNb_n[n] - d);
                    const int idx2 = atomicAdd(&cntC[ci], 1);
                    if (idx2 < CAPL) candC[ci * CAPL + idx2] = val;
                    else {
                        const int g = atomicAdd(&cnt_g[c0 + ci], 1);
                        if (g < CAPG) cand_g[(size_t)(c0 + ci) * CAPG + g] = val;
                    }
                }
            }
        }

    __syncthreads();
    if (tid < 128) {
        {   // row-side writeout
            const int row = r0 + tid;
            const int c = (cntR[tid] < CAPL) ? cntR[tid] : CAPL;
            if (c > 0) {
                const int base = atomicAdd(&cnt_g[row], c);
                for (int q = 0; q < c; ++q) {
                    const int s = base + q;
                    if (s < CAPG) cand_g[(size_t)row * CAPG + s] = candR[tid * CAPL + q];
                }
            }
        }
        if (!diag) {   // col-side writeout
            const int row = c0 + tid;
            const int c = (cntC[tid] < CAPL) ? cntC[tid] : CAPL;
            if (c > 0) {
                const int base = atomicAdd(&cnt_g[row], c);
                for (int q = 0; q < c; ++q) {
                    const int s = base + q;
                    if (s < CAPG) cand_g[(size_t)row * CAPG + s] = candC[tid * CAPL + q];
                }
            }
        }
    }
}

// ---------------- kernel 3: finalize + fused exact rescue ----
__global__ __launch_bounds__(256) void finalize_kernel(const float* __restrict__ cand_g,
                                                       const int* __restrict__ cnt_g,
                                                       const u16* __restrict__ Xh,
                                                       const float* __restrict__ norms,
                                                       float* __restrict__ out) {
    const int tid  = threadIdx.x;
    const int lane = tid & 63;
    const int row  = blockIdx.x * 4 + (tid >> 6);

    int cnt = cnt_g[row];
    const bool bad = (cnt < TOPK) || (cnt > CAPG);   // wave-uniform
    const float INFV = __uint_as_float(0x7F800000u);

    float a0v, a20v, S21v;
    if (bad) {
        // ---- exact rescue: lane scans cols lane, lane+64, ... ----
        const float nR = norms[row];
        float t[TOPK];
#pragma unroll
        for (int q = 0; q < TOPK; ++q) t[q] = 3e38f;
        for (int c = lane; c < N_PTS; c += 64) {
            const u16* xa = Xh + (size_t)row * D_DIM;
            const u16* xb = Xh + (size_t)c * D_DIM;
            float dot = 0.f;
            for (int d = 0; d < D_DIM; ++d) {
                const float a = (float)__builtin_bit_cast(_Float16, xa[d]);
                const float b = (float)__builtin_bit_cast(_Float16, xb[d]);
                dot += a * b;
            }
            topk_insert(t, fmaxf(nR + norms[c] - 2.0f * dot, 0.0f));
        }
        unsigned lo = 0, hi = 0x7F7FFFFFu;
        for (int it = 0; it < 31; ++it) {
            const unsigned mid = (lo + hi) >> 1;
            int c = 0;
#pragma unroll
            for (int q = 0; q < TOPK; ++q) c += (__float_as_uint(t[q]) <= mid);
            c = wred_sum_i(c);
            if (c >= TOPK) hi = mid; else lo = mid + 1;
        }
        int clt = 0;
        float slt = 0.f, mn = INFV;
#pragma unroll
        for (int q = 0; q < TOPK; ++q) {
            if (__float_as_uint(t[q]) < lo) {
                clt += 1;
                slt += sqrtf(fmaxf(t[q], 1e-12f));
            }
            mn = fminf(mn, t[q]);
        }
        clt = wred_sum_i(clt);
        slt = wred_sum_f(slt);
        mn  = wred_min_f(mn);
        a20v = sqrtf(fmaxf(__uint_as_float(lo), 1e-12f));
        a0v  = sqrtf(fmaxf(mn, 1e-12f));
        S21v = slt + (float)(TOPK - clt) * a20v;
    } else {
        float v[3];
        unsigned bb[3];
#pragma unroll
        for (int j = 0; j < 3; ++j) {
            const int s = lane + 64 * j;
            v[j] = (s < cnt) ? fmaxf(cand_g[(size_t)row * CAPG + s], 0.0f) : INFV;
            bb[j] = __float_as_uint(v[j]);
        }
        unsigned lo = 0, hi = 0x7F7FFFFFu;
#pragma unroll
        for (int it = 0; it < 31; ++it) {
            const unsigned mid = (lo + hi) >> 1;
            int c = 0;
#pragma unroll
            for (int j = 0; j < 3; ++j) c += (bb[j] <= mid);
            c = wred_sum_i(c);
            if (c >= TOPK) hi = mid; else lo = mid + 1;
        }
        int clt = 0;
        float slt = 0.f, mn = INFV;
#pragma unroll
        for (int j = 0; j < 3; ++j) {
            if (bb[j] < lo) {
                clt += 1;
                slt += sqrtf(fmaxf(v[j], 1e-12f));
            }
            mn = fminf(mn, v[j]);
        }
        clt = wred_sum_i(clt);
        slt = wred_sum_f(slt);
        mn  = wred_min_f(mn);
        a20v = sqrtf(fmaxf(__uint_as_float(lo), 1e-12f));
        a0v  = sqrtf(fmaxf(mn, 1e-12f));
        S21v = slt + (float)(TOPK - clt) * a20v;
    }

    if (lane == 0) {
        const float m   = (S21v - a0v - a20v) * (1.0f / 19.0f);
        const float lid = m / (a20v - m);
        out[row] = -fabsf(logf(lid));
    }
}

extern "C" void kernel_launch(void* const* d_in, const int* in_sizes, int n_in,
                              void* d_out, int out_size, void* d_ws, size_t ws_size,
                              hipStream_t stream) {
    const float* X = (const float*)d_in[0];
    float* out = (float*)d_out;
    char* ws = (char*)d_ws;

    u16*   Xh     = (u16*)ws;                     // 12,582,912 B
    float* norms  = (float*)(ws + 12582912);      //     32,768 B
    int*   cnt_g  = (int*)(ws + 12615680);        //     32,768 B
    float* cand_g = (float*)(ws + 12648448);      //  6,291,456 B (8192 x 192 f32)
                                                  // total 18,939,904 B

    prep_kernel<<<N_PTS / 4, 256, 0, stream>>>(X, Xh, norms, cnt_g);
    gemm_filter_sym<<<2080, 256, 0, stream>>>(Xh, norms, cand_g, cnt_g);
    finalize_kernel<<<N_PTS / 4, 256, 0, stream>>>(cand_g, cnt_g, Xh, norms, out);
}

// Round 17
// 113.532 us; speedup vs baseline: 1.9997x; 1.9997x over previous
//
#include <hip/hip_runtime.h>
#include <hip/hip_fp16.h>

typedef unsigned short u16;
using f32x4 = __attribute__((ext_vector_type(4))) float;
using half8 = __attribute__((ext_vector_type(8))) _Float16;
using us4   = __attribute__((ext_vector_type(4))) unsigned short;

#define N_PTS 8192
#define D_DIM 768
#define TOPK  21
#define KSTEPS 12
#define CAPL  5          // lambda/tile-side ~0.94 -> P(>5) ~3e-4, ~200 spills total
#define CAPG  192        // E[cand/row]=60, +17 sigma
#define ZTAU  2.44f      // tau_i = n_i + 768 - ZTAU*sqrt(1536+4 n_i) -> E=60/row

// ---------------- async global->LDS (16B per lane) ----------------
__device__ __forceinline__ void gload16(const void* g, void* l) {
    __builtin_amdgcn_global_load_lds(
        (const __attribute__((address_space(1))) void*)g,
        (__attribute__((address_space(3))) void*)l,
        16, 0, 0);
}

// ---------------- wave (64-lane) reductions ----------------
__device__ __forceinline__ int wred_sum_i(int c) {
#pragma unroll
    for (int o = 32; o >= 1; o >>= 1) c += __shfl_xor(c, o, 64);
    return c;
}
__device__ __forceinline__ float wred_sum_f(float c) {
#pragma unroll
    for (int o = 32; o >= 1; o >>= 1) c += __shfl_xor(c, o, 64);
    return c;
}
__device__ __forceinline__ float wred_min_f(float c) {
#pragma unroll
    for (int o = 32; o >= 1; o >>= 1) c = fminf(c, __shfl_xor(c, o, 64));
    return c;
}

// branch-free sorted top-k insert (ascending), rescue path only
__device__ __forceinline__ void topk_insert(float (&t)[TOPK], float x) {
    if (x >= t[TOPK - 1]) return;
#pragma unroll
    for (int i = TOPK - 1; i >= 1; --i) {
        float tp = t[i - 1];
        t[i] = (x < tp) ? tp : fminf(x, t[i]);
    }
    t[0] = fminf(t[0], x);
}

// ---------------- kernel 1: fp32 -> fp16 + row norms (vectorized) ----
__global__ __launch_bounds__(256) void prep_kernel(const float* __restrict__ X,
                                                   u16* __restrict__ Xh,
                                                   float* __restrict__ norms,
                                                   int* __restrict__ cnt_g) {
    const int tid  = threadIdx.x;
    const int lane = tid & 63;
    const int row  = blockIdx.x * 4 + (tid >> 6);
    const float4* xr = (const float4*)(X + (size_t)row * D_DIM);
    us4* hr = (us4*)(Xh + (size_t)row * D_DIM);
    float s = 0.f;
#pragma unroll
    for (int j = 0; j < 3; ++j) {
        const float4 v = xr[lane + j * 64];
        _Float16 h0 = (_Float16)v.x, h1 = (_Float16)v.y,
                 h2 = (_Float16)v.z, h3 = (_Float16)v.w;
        us4 u;
        u[0] = __builtin_bit_cast(u16, h0);
        u[1] = __builtin_bit_cast(u16, h1);
        u[2] = __builtin_bit_cast(u16, h2);
        u[3] = __builtin_bit_cast(u16, h3);
        hr[lane + j * 64] = u;
        const float f0 = (float)h0, f1 = (float)h1, f2 = (float)h2, f3 = (float)h3;
        s += f0 * f0 + f1 * f1 + f2 * f2 + f3 * f3;
    }
#pragma unroll
    for (int o = 32; o >= 1; o >>= 1) s += __shfl_down(s, o, 64);
    if (lane == 0) {
        norms[row] = s;
        cnt_g[row] = 0;
    }
}

// ---------------- kernel 2: SYMMETRIC upper-triangle GEMM + two-sided filter ----
// 2080 = 64*65/2 tiles (i<=j). LDS exactly 40960 B -> 4 blocks/CU.
// Per-row tau via hC = 0.5*(768 - Z*sqrt(1536+4n)); compares in acc-domain.
__global__ __launch_bounds__(256, 4) void gemm_filter_sym(const u16* __restrict__ Xh,
                                                          const float* __restrict__ norms,
                                                          float* __restrict__ cand_g,
                                                          int* __restrict__ cnt_g) {
    __shared__ __align__(16) u16 As[128 * 64];       // 16384 B
    __shared__ __align__(16) u16 Bs[128 * 64];       // 16384 B
    __shared__ float candR[128 * CAPL];              //  2560 B
    __shared__ float candC[128 * CAPL];              //  2560 B
    __shared__ int   cntR[128];                      //   512 B
    __shared__ int   cntC[128];                      //   512 B
    __shared__ float hNa[128], hNb[128], hCr[128], hCc[128];  // 2048 B => 40960

    const int tid  = threadIdx.x;
    const int lane = tid & 63;
    const int wid  = tid >> 6;
    const int wr   = wid >> 1;
    const int wc   = wid & 1;
    const int l16  = lane >> 4;
    const int l15  = lane & 15;

    // XCD swizzle (2080 = 8 * 260) then triangular decode: b = j*(j+1)/2 + i, i<=j
    const int b = (blockIdx.x & 7) * 260 + (blockIdx.x >> 3);
    int j = (int)((sqrtf(8.0f * (float)b + 1.0f) - 1.0f) * 0.5f);
    while ((j + 1) * (j + 2) / 2 <= b) ++j;
    while (j * (j + 1) / 2 > b) --j;
    const int i = b - j * (j + 1) / 2;
    const int r0 = i * 128;
    const int c0 = j * 128;
    const bool diag = (i == j);

    if (tid < 128) {
        const float na = norms[r0 + tid];
        const float nb = norms[c0 + tid];
        hNa[tid] = 0.5f * na;
        hNb[tid] = 0.5f * nb;
        hCr[tid] = 0.5f * (768.0f - ZTAU * sqrtf(1536.0f + 4.0f * na));
        hCc[tid] = 0.5f * (768.0f - ZTAU * sqrtf(1536.0f + 4.0f * nb));
        cntR[tid] = 0;
        cntC[tid] = 0;
    }

    // staging geometry: 8 lanes per 128B row; T2 source-side XOR swizzle
    const int rb  = tid >> 3;
    const int chS = (tid & 7) ^ ((tid >> 3) & 7);
    const int lofs = tid * 8;

    f32x4 acc[4][4];
#pragma unroll
    for (int m = 0; m < 4; ++m)
#pragma unroll
        for (int n = 0; n < 4; ++n) {
            f32x4 z = {0.f, 0.f, 0.f, 0.f};
            acc[m][n] = z;
        }

    for (int ks = 0; ks < KSTEPS; ++ks) {
        const int kofs = ks * 64 + chS * 8;
#pragma unroll
        for (int it = 0; it < 4; ++it) {
            const int r = it * 32 + rb;
            gload16(Xh + (size_t)(r0 + r) * D_DIM + kofs, &As[it * 2048 + lofs]);
            gload16(Xh + (size_t)(c0 + r) * D_DIM + kofs, &Bs[it * 2048 + lofs]);
        }
        __syncthreads();
#pragma unroll
        for (int kk = 0; kk < 2; ++kk) {
            half8 af[4], bf[4];
#pragma unroll
            for (int m = 0; m < 4; ++m) {
                const int ra = wr * 64 + m * 16 + l15;
                const int ch = (kk * 4 + l16) ^ (ra & 7);
                af[m] = *reinterpret_cast<const half8*>(&As[ra * 64 + ch * 8]);
            }
#pragma unroll
            for (int n = 0; n < 4; ++n) {
                const int rc = wc * 64 + n * 16 + l15;
                const int ch = (kk * 4 + l16) ^ (rc & 7);
                bf[n] = *reinterpret_cast<const half8*>(&Bs[rc * 64 + ch * 8]);
            }
#pragma unroll
            for (int m = 0; m < 4; ++m)
#pragma unroll
                for (int n = 0; n < 4; ++n)
                    acc[m][n] = __builtin_amdgcn_mfma_f32_16x16x32_f16(af[m], bf[n], acc[m][n], 0, 0, 0);
        }
        __syncthreads();
    }

    // ---- two-sided filter epilogue, acc-domain compares ----
    float hNb_n[4], hCc_n[4];
#pragma unroll
    for (int n = 0; n < 4; ++n) {
        const int ci = wc * 64 + n * 16 + l15;
        hNb_n[n] = hNb[ci];
        hCc_n[n] = hCc[ci];
    }

#pragma unroll
    for (int m = 0; m < 4; ++m)
#pragma unroll
        for (int r = 0; r < 4; ++r) {
            const int ri = wr * 64 + m * 16 + l16 * 4 + r;
            const float hna = hNa[ri];
            const float hcr = hCr[ri];
#pragma unroll
            for (int n = 0; n < 4; ++n) {
                const float d = acc[m][n][r];
                // rowHit: d2 < tau_row  <=>  acc > 0.5*nB - 0.5*C_row
                if (d > hNb_n[n] - hcr) {
                    const float val = 2.0f * (hna + hNb_n[n] - d);
                    const int idx2 = atomicAdd(&cntR[ri], 1);
                    if (idx2 < CAPL) candR[ri * CAPL + idx2] = val;
                    else {
                        const int g = atomicAdd(&cnt_g[r0 + ri], 1);
                        if (g < CAPG) cand_g[(size_t)(r0 + ri) * CAPG + g] = val;
                    }
                }
                // colHit: d2 < tau_col  <=>  acc > 0.5*nA - 0.5*C_col
                if (!diag && d > hna - hCc_n[n]) {
                    const int ci = wc * 64 + n * 16 + l15;
                    const float val = 2.0f * (hna + hNb_n[n] - d);
                    const int idx2 = atomicAdd(&cntC[ci], 1);
                    if (idx2 < CAPL) candC[ci * CAPL + idx2] = val;
                    else {
                        const int g = atomicAdd(&cnt_g[c0 + ci], 1);
                        if (g < CAPG) cand_g[(size_t)(c0 + ci) * CAPG + g] = val;
                    }
                }
            }
        }

    __syncthreads();
    if (tid < 128) {
        {   // row-side writeout
            const int row = r0 + tid;
            const int c = (cntR[tid] < CAPL) ? cntR[tid] : CAPL;
            if (c > 0) {
                const int base = atomicAdd(&cnt_g[row], c);
                for (int q = 0; q < c; ++q) {
                    const int s = base + q;
                    if (s < CAPG) cand_g[(size_t)row * CAPG + s] = candR[tid * CAPL + q];
                }
            }
        }
        if (!diag) {   // col-side writeout
            const int row = c0 + tid;
            const int c = (cntC[tid] < CAPL) ? cntC[tid] : CAPL;
            if (c > 0) {
                const int base = atomicAdd(&cnt_g[row], c);
                for (int q = 0; q < c; ++q) {
                    const int s = base + q;
                    if (s < CAPG) cand_g[(size_t)row * CAPG + s] = candC[tid * CAPL + q];
                }
            }
        }
    }
}

// ---------------- kernel 3: finalize + fused exact rescue ----
// One wave per row. If cnt<21 or cnt>CAPG (never in practice), the wave
// brute-forces the exact top-21; else normal candidate-stats path.
__global__ __launch_bounds__(256) void finalize_kernel(const float* __restrict__ cand_g,
                                                       const int* __restrict__ cnt_g,
                                                       const u16* __restrict__ Xh,
                                                       const float* __restrict__ norms,
                                                       float* __restrict__ out) {
    const int tid  = threadIdx.x;
    const int lane = tid & 63;
    const int row  = blockIdx.x * 4 + (tid >> 6);

    int cnt = cnt_g[row];
    const bool bad = (cnt < TOPK) || (cnt > CAPG);   // wave-uniform
    const float INFV = __uint_as_float(0x7F800000u);

    float a0v, a20v, S21v;
    if (bad) {
        // ---- exact rescue: lane scans cols lane, lane+64, ... ----
        const float nR = norms[row];
        float t[TOPK];
#pragma unroll
        for (int q = 0; q < TOPK; ++q) t[q] = 3e38f;
        for (int c = lane; c < N_PTS; c += 64) {
            const u16* xa = Xh + (size_t)row * D_DIM;
            const u16* xb = Xh + (size_t)c * D_DIM;
            float dot = 0.f;
            for (int d = 0; d < D_DIM; ++d) {
                const float a = (float)__builtin_bit_cast(_Float16, xa[d]);
                const float b = (float)__builtin_bit_cast(_Float16, xb[d]);
                dot += a * b;
            }
            topk_insert(t, fmaxf(nR + norms[c] - 2.0f * dot, 0.0f));
        }
        unsigned lo = 0, hi = 0x7F7FFFFFu;
        for (int it = 0; it < 31; ++it) {
            const unsigned mid = (lo + hi) >> 1;
            int c = 0;
#pragma unroll
            for (int q = 0; q < TOPK; ++q) c += (__float_as_uint(t[q]) <= mid);
            c = wred_sum_i(c);
            if (c >= TOPK) hi = mid; else lo = mid + 1;
        }
        int clt = 0;
        float slt = 0.f, mn = INFV;
#pragma unroll
        for (int q = 0; q < TOPK; ++q) {
            if (__float_as_uint(t[q]) < lo) {
                clt += 1;
                slt += sqrtf(fmaxf(t[q], 1e-12f));
            }
            mn = fminf(mn, t[q]);
        }
        clt = wred_sum_i(clt);
        slt = wred_sum_f(slt);
        mn  = wred_min_f(mn);
        a20v = sqrtf(fmaxf(__uint_as_float(lo), 1e-12f));
        a0v  = sqrtf(fmaxf(mn, 1e-12f));
        S21v = slt + (float)(TOPK - clt) * a20v;
    } else {
        float v[3];
        unsigned bb[3];
#pragma unroll
        for (int j = 0; j < 3; ++j) {
            const int s = lane + 64 * j;
            v[j] = (s < cnt) ? fmaxf(cand_g[(size_t)row * CAPG + s], 0.0f) : INFV;
            bb[j] = __float_as_uint(v[j]);
        }
        unsigned lo = 0, hi = 0x7F7FFFFFu;
#pragma unroll
        for (int it = 0; it < 31; ++it) {
            const unsigned mid = (lo + hi) >> 1;
            int c = 0;
#pragma unroll
            for (int j = 0; j < 3; ++j) c += (bb[j] <= mid);
            c = wred_sum_i(c);
            if (c >= TOPK) hi = mid; else lo = mid + 1;
        }
        int clt = 0;
        float slt = 0.f, mn = INFV;
#pragma unroll
        for (int j = 0; j < 3; ++j) {
            if (bb[j] < lo) {
                clt += 1;
                slt += sqrtf(fmaxf(v[j], 1e-12f));
            }
            mn = fminf(mn, v[j]);
        }
        clt = wred_sum_i(clt);
        slt = wred_sum_f(slt);
        mn  = wred_min_f(mn);
        a20v = sqrtf(fmaxf(__uint_as_float(lo), 1e-12f));
        a0v  = sqrtf(fmaxf(mn, 1e-12f));
        S21v = slt + (float)(TOPK - clt) * a20v;
    }

    if (lane == 0) {
        const float m   = (S21v - a0v - a20v) * (1.0f / 19.0f);
        const float lid = m / (a20v - m);
        out[row] = -fabsf(logf(lid));
    }
}

extern "C" void kernel_launch(void* const* d_in, const int* in_sizes, int n_in,
                              void* d_out, int out_size, void* d_ws, size_t ws_size,
                              hipStream_t stream) {
    const float* X = (const float*)d_in[0];
    float* out = (float*)d_out;
    char* ws = (char*)d_ws;

    u16*   Xh     = (u16*)ws;                     // 12,582,912 B
    float* norms  = (float*)(ws + 12582912);      //     32,768 B
    int*   cnt_g  = (int*)(ws + 12615680);        //     32,768 B
    float* cand_g = (float*)(ws + 12648448);      //  6,291,456 B (8192 x 192 f32)
                                                  // total 18,939,904 B

    prep_kernel<<<N_PTS / 4, 256, 0, stream>>>(X, Xh, norms, cnt_g);
    gemm_filter_sym<<<2080, 256, 0, stream>>>(Xh, norms, cand_g, cnt_g);
    finalize_kernel<<<N_PTS / 4, 256, 0, stream>>>(cand_g, cnt_g, Xh, norms, out);
}